// Round 6
// baseline (297.386 us; speedup 1.0000x reference)
//
#include <hip/hip_runtime.h>

typedef float  f32x4  __attribute__((ext_vector_type(4)));
typedef __bf16 bf16x8 __attribute__((ext_vector_type(8)));
typedef unsigned short u16x8 __attribute__((ext_vector_type(8)));
typedef unsigned int   u32x4 __attribute__((ext_vector_type(4)));

__device__ inline unsigned short f2b(float f) {
    unsigned u = __builtin_bit_cast(unsigned, f);
    u += 0x7fffu + ((u >> 16) & 1u);       // round-to-nearest-even
    return (unsigned short)(u >> 16);
}

// single-instruction packed f32->bf16 (RTNE, low half = first operand)
__device__ inline unsigned cvtpk(float a, float b) {
    unsigned r;
    asm("v_cvt_pk_bf16_f32 %0, %1, %2" : "=v"(r) : "v"(a), "v"(b));
    return r;
}

__device__ inline f32x4 mfma16(bf16x8 a, bf16x8 b, f32x4 c) {
    return __builtin_amdgcn_mfma_f32_16x16x32_bf16(a, b, c, 0, 0, 0);
}

__device__ inline bf16x8 cvt8(f32x4 a, f32x4 b) {
    u32x4 w;
    w[0] = cvtpk(a[0], a[1]); w[1] = cvtpk(a[2], a[3]);
    w[2] = cvtpk(b[0], b[1]); w[3] = cvtpk(b[2], b[3]);
    return __builtin_bit_cast(bf16x8, w);
}

__device__ inline bf16x8 ldsA(const unsigned short* base, int frag, int lane) {
    return __builtin_bit_cast(bf16x8,
        *reinterpret_cast<const u16x8*>(base + ((frag * 64 + lane) << 3)));
}

__device__ inline void atom_pk(unsigned short* p, unsigned d) {
    asm volatile("global_atomic_pk_add_bf16 %0, %1, off" :: "v"(p), "v"(d) : "memory");
}

// ===================== CSR build (fused) =====================
// k_prep: f32->bf16 convert of h, zero aggb, row histogram -- one launch.
__global__ void k_prep(const float* __restrict__ h, unsigned short* __restrict__ hb,
                       u16x8* __restrict__ aggb8,
                       const int* __restrict__ erow, int* __restrict__ cnt,
                       int n8, int E)
{
    int i = blockIdx.x * 256 + threadIdx.x;
    if (i < n8) {
        const f32x4* p = reinterpret_cast<const f32x4*>(h + (size_t)i * 8);
        bf16x8 v = cvt8(p[0], p[1]);
        reinterpret_cast<u16x8*>(hb)[i] = __builtin_bit_cast(u16x8, v);
        aggb8[i] = (u16x8){0, 0, 0, 0, 0, 0, 0, 0};
    }
    if (i < E) atomicAdd(&cnt[erow[i]], 1);
}

// single-block exclusive scan cnt[0..N) -> woff (1024 threads)
__global__ void k_scan(const int* __restrict__ cnt, int* __restrict__ woff, int N)
{
    __shared__ int wsum[16];
    const int t = threadIdx.x;
    const int lane = t & 63, w = t >> 6;
    const int chunk = (N + 1023) >> 10;
    const int lo = t * chunk;
    const int hi = (lo + chunk < N) ? lo + chunk : N;
    int s = 0;
    for (int i = lo; i < hi; ++i) s += cnt[i];
    int sc = s;
#pragma unroll
    for (int d = 1; d < 64; d <<= 1) {
        int v = __shfl_up(sc, d, 64);
        if (lane >= d) sc += v;
    }
    if (lane == 63) wsum[w] = sc;
    __syncthreads();
    if (w == 0 && lane < 16) {
        int v = wsum[lane];
        int scw = v;
#pragma unroll
        for (int d = 1; d < 16; d <<= 1) {
            int u = __shfl_up(scw, d, 16);
            if (lane >= d) scw += u;
        }
        wsum[lane] = scw - v;             // exclusive wave prefix
    }
    __syncthreads();
    int run = wsum[w] + (sc - s);
    for (int i = lo; i < hi; ++i) { woff[i] = run; run += cnt[i]; }
}

// scatter edges into row-sorted order (pack row|col<<16); zero cacc (fused)
__global__ void k_scatter(const int* __restrict__ erow, const int* __restrict__ ecol,
                          int* __restrict__ woff, unsigned* __restrict__ spack,
                          float* __restrict__ cacc, int N, int E)
{
    int i = blockIdx.x * 256 + threadIdx.x;
    if (i < N)
        *reinterpret_cast<f32x4*>(cacc + (size_t)i * 4) = (f32x4){0.f, 0.f, 0.f, 0.f};
    if (i < E) {
        int r = erow[i];
        int pos = atomicAdd(&woff[r], 1);
        spack[pos] = (unsigned)r | ((unsigned)ecol[i] << 16);
    }
}

// ========== SORTED EDGE PASS: R0 pipeline + sel-MFMA partials + pk-bf16
// leader atomics into workspace (L2-merged; d_out is fine-grained -- R4 lesson).
__global__ __launch_bounds__(512, 2) void egcl_edge_srt(
    const unsigned short* __restrict__ hb,
    const float* __restrict__ coord,
    const unsigned* __restrict__ spack,
    const float* __restrict__ We1, const float* __restrict__ be1,
    const float* __restrict__ We2, const float* __restrict__ be2,
    const float* __restrict__ Wc1, const float* __restrict__ bc1,
    const float* __restrict__ Wc2,
    unsigned short* __restrict__ aggb, float* __restrict__ cacc, int E)
{
    __shared__ __align__(16) unsigned short A1[16 * 512];
    __shared__ __align__(16) unsigned short A2[8 * 512];
    __shared__ __align__(16) unsigned short A3[8 * 512];
    __shared__ __align__(16) float bv[5][64];
    __shared__ __align__(16) unsigned stl[8][34 * 16];   // per-wave stash [cp][slot^swz]

    const int t = threadIdx.x;
    for (int i = t; i < 8192; i += 512) {
        int j = i & 7, lane = (i >> 3) & 63, fi = i >> 9;
        int mt = fi >> 2, ks = fi & 3;
        int in_ch = ks * 32 + ((lane >> 4) << 3) + j;
        int out   = mt * 16 + (lane & 15);
        A1[i] = f2b(We1[in_ch * 64 + out]);
    }
    for (int i = t; i < 4096; i += 512) {
        int j = i & 7, lane = (i >> 3) & 63, fi = i >> 9;
        int mt = fi >> 1, ks = fi & 1;
        int c   = (ks * 2 + (j >> 2)) * 16 + ((lane >> 4) & 3) * 4 + (j & 3);
        int out = mt * 16 + (lane & 15);
        A2[i] = f2b(We2[c * 64 + out]);
        A3[i] = f2b(Wc1[c * 64 + out]);
    }
    if (t < 64) {
        bv[0][t] = be1[t]; bv[1][t] = We1[128 * 64 + t];
        bv[2][t] = be2[t]; bv[3][t] = bc1[t]; bv[4][t] = Wc2[t];
    }
    __syncthreads();

    const int lane = t & 63;
    const int l16 = lane & 15, lq = lane >> 4;
    const int stride = gridDim.x * 8;
    const int wid = (blockIdx.x << 3) + (t >> 6);
    const int ntile = E >> 4;
    const int last = ntile - 1;
    unsigned* st = stl[t >> 6];

    int tile = wid;
    if (tile >= ntile) return;

    // ---------------- prologue: tile 0 data + tile 1 indices
    int eC = (tile << 4) + l16;
    unsigned pC = spack[eC];
    int rC = (int)(pC & 0xffffu), cC = (int)(pC >> 16);
    u16x8 hr0, hr1, hc0, hc1;
    {
        const u16x8* hr = reinterpret_cast<const u16x8*>(hb + (size_t)rC * 64);
        const u16x8* hc = reinterpret_cast<const u16x8*>(hb + (size_t)cC * 64);
        hr0 = hr[lq]; hr1 = hr[4 + lq]; hc0 = hc[lq]; hc1 = hc[4 + lq];
    }
    float px = 0.f, py = 0.f, pz = 0.f;
    if (lq < 2) {
        int node = (lq == 0) ? rC : cC;
        const float* pp = coord + (size_t)node * 3;
        px = pp[0]; py = pp[1]; pz = pp[2];
    }
    int t1 = tile + stride;
    int tn = (t1 < ntile) ? t1 : last;
    unsigned pN = spack[(tn << 4) + l16];
    int rN = (int)(pN & 0xffffu), cN = (int)(pN >> 16);

    for (; tile < ntile; ) {
        // ---- stage 1: issue next tile's h/coord loads
        u16x8 nr0, nr1, nc0, nc1;
        {
            const u16x8* hr = reinterpret_cast<const u16x8*>(hb + (size_t)rN * 64);
            const u16x8* hc = reinterpret_cast<const u16x8*>(hb + (size_t)cN * 64);
            nr0 = hr[lq]; nr1 = hr[4 + lq]; nc0 = hc[lq]; nc1 = hc[4 + lq];
        }
        float npx = 0.f, npy = 0.f, npz = 0.f;
        if (lq < 2) {
            int node = (lq == 0) ? rN : cN;
            const float* pp = coord + (size_t)node * 3;
            npx = pp[0]; npy = pp[1]; npz = pp[2];
        }
        // ---- stage 2: issue tile+2 index loads
        int t2 = tile + 2 * stride;
        int t2c = (t2 < ntile) ? t2 : last;
        unsigned pNN = spack[(t2c << 4) + l16];
        int rNN = (int)(pNN & 0xffffu), cNN = (int)(pNN >> 16);

        // ---- stage 3: compute current tile
        float prx = __shfl(px, l16, 64), pry = __shfl(py, l16, 64), prz = __shfl(pz, l16, 64);
        float pcx = __shfl(px, 16 + l16, 64), pcy = __shfl(py, 16 + l16, 64), pcz = __shfl(pz, 16 + l16, 64);
        float dx = prx - pcx, dy = pry - pcy, dz = prz - pcz;
        float rad = dx * dx + dy * dy + dz * dz;

        bf16x8 bR[2] = { __builtin_bit_cast(bf16x8, hr0), __builtin_bit_cast(bf16x8, hr1) };
        bf16x8 bC[2] = { __builtin_bit_cast(bf16x8, hc0), __builtin_bit_cast(bf16x8, hc1) };

        // layer 1
        f32x4 a1[4];
#pragma unroll
        for (int mt = 0; mt < 4; ++mt)
            a1[mt] = *reinterpret_cast<const f32x4*>(&bv[0][mt * 16 + lq * 4]);
#pragma unroll
        for (int ks = 0; ks < 2; ++ks)
#pragma unroll
            for (int mt = 0; mt < 4; ++mt)
                a1[mt] = mfma16(ldsA(A1, mt * 4 + ks, lane), bR[ks], a1[mt]);
#pragma unroll
        for (int ks = 0; ks < 2; ++ks)
#pragma unroll
            for (int mt = 0; mt < 4; ++mt)
                a1[mt] = mfma16(ldsA(A1, mt * 4 + 2 + ks, lane), bC[ks], a1[mt]);
#pragma unroll
        for (int mt = 0; mt < 4; ++mt) {
            f32x4 wv = *reinterpret_cast<const f32x4*>(&bv[1][mt * 16 + lq * 4]);
#pragma unroll
            for (int rr = 0; rr < 4; ++rr)
                a1[mt][rr] = fmaxf(a1[mt][rr] + rad * wv[rr], 0.f);
        }

        // layer 2
        bf16x8 b2[2] = { cvt8(a1[0], a1[1]), cvt8(a1[2], a1[3]) };
        f32x4 a2[4];
#pragma unroll
        for (int mt = 0; mt < 4; ++mt)
            a2[mt] = *reinterpret_cast<const f32x4*>(&bv[2][mt * 16 + lq * 4]);
#pragma unroll
        for (int ks = 0; ks < 2; ++ks)
#pragma unroll
            for (int mt = 0; mt < 4; ++mt)
                a2[mt] = mfma16(ldsA(A2, mt * 2 + ks, lane), b2[ks], a2[mt]);
#pragma unroll
        for (int mt = 0; mt < 4; ++mt)
#pragma unroll
            for (int rr = 0; rr < 4; ++rr)
                a2[mt][rr] = fmaxf(a2[mt][rr], 0.f);

        // ---- stash a2 (channel-pair major, swizzled): st[cp][l16 ^ (cp&12)]
#pragma unroll
        for (int mt = 0; mt < 4; ++mt) {
            int cp0 = mt * 8 + lq * 2;
            int sw  = l16 ^ (cp0 & 12);
            st[(cp0 + 0) * 16 + sw] = cvtpk(a2[mt][0], a2[mt][1]);
            st[(cp0 + 1) * 16 + sw] = cvtpk(a2[mt][2], a2[mt][3]);
        }

        // ---- gate (MFMAs overlap the stash writes)
        bf16x8 b3[2] = { cvt8(a2[0], a2[1]), cvt8(a2[2], a2[3]) };
        f32x4 a3[4];
#pragma unroll
        for (int mt = 0; mt < 4; ++mt)
            a3[mt] = *reinterpret_cast<const f32x4*>(&bv[3][mt * 16 + lq * 4]);
#pragma unroll
        for (int ks = 0; ks < 2; ++ks)
#pragma unroll
            for (int mt = 0; mt < 4; ++mt)
                a3[mt] = mfma16(ldsA(A3, mt * 2 + ks, lane), b3[ks], a3[mt]);
        float gg = 0.f;
#pragma unroll
        for (int mt = 0; mt < 4; ++mt) {
            f32x4 wv = *reinterpret_cast<const f32x4*>(&bv[4][mt * 16 + lq * 4]);
#pragma unroll
            for (int rr = 0; rr < 4; ++rr)
                gg += fmaxf(a3[mt][rr], 0.f) * wv[rr];
        }
        gg += __shfl_xor(gg, 16, 64);
        gg += __shfl_xor(gg, 32, 64);

        float dsel = (lq == 0) ? dx : (lq == 1) ? dy : dz;
        float val  = fminf(fmaxf(dsel * gg, -100.f), 100.f);

        // ---- coord stash rows {x,y},{z,1}: cp = 32, 33 (swizzle = 0 there)
        float vy = __shfl(val, 16 + l16, 64);          // y from lq==1 lane
        if (lq == 0) st[32 * 16 + l16] = cvtpk(val, vy);
        if (lq == 2) st[33 * 16 + l16] = cvtpk(val, 1.0f);

        // ---- selection fragment: sel[k][n] = (row(edge k) == row(edge n))
        u16x8 sv;
#pragma unroll
        for (int j = 0; j < 8; ++j) {
            int ks = lq * 8 + j;
            int rk = __shfl(rC, ks & 15, 64);
            sv[j] = (ks < 16 && rk == rC) ? (unsigned short)0x3F80 : (unsigned short)0;
        }
        bf16x8 self = __builtin_bit_cast(bf16x8, sv);

        // ---- per-tile partial sums: 5 MFMAs (4 channel tiles + coord tile)
        f32x4 pg[5];
#pragma unroll
        for (int k = 0; k < 5; ++k) pg[k] = (f32x4){0.f, 0.f, 0.f, 0.f};
        const int elo = (lq & 1) << 3;
#pragma unroll
        for (int tt = 0; tt < 5; ++tt) {
            int cpb = (tt < 4) ? (tt * 8 + (l16 >> 1)) : (32 + ((l16 >> 1) & 1));
            int c   = cpb & 12;
            u32x4 wa = *reinterpret_cast<const u32x4*>(st + cpb * 16 + (elo ^ c));
            u32x4 wb = *reinterpret_cast<const u32x4*>(st + cpb * 16 + ((elo + 4) ^ c));
            u16x8 av;
#pragma unroll
            for (int j = 0; j < 4; ++j) {
                av[j]     = (l16 & 1) ? (unsigned short)(wa[j] >> 16)
                                      : (unsigned short)(wa[j] & 0xffffu);
                av[4 + j] = (l16 & 1) ? (unsigned short)(wb[j] >> 16)
                                      : (unsigned short)(wb[j] & 0xffffu);
            }
            pg[tt] = mfma16(__builtin_bit_cast(bf16x8, av), self, pg[tt]);
        }

        // ---- write partials back to the stash (feat stash fully consumed)
#pragma unroll
        for (int mt = 0; mt < 4; ++mt) {
            int cp0 = mt * 8 + lq * 2;
            int sw  = l16 ^ (cp0 & 12);
            st[(cp0 + 0) * 16 + sw] = cvtpk(pg[mt][0], pg[mt][1]);
            st[(cp0 + 1) * 16 + sw] = cvtpk(pg[mt][2], pg[mt][3]);
        }

        // ---- leader detection (run starts within the tile)
        int rprev = __shfl(rC, (lane & 48) | ((l16 + 15) & 15), 64);
        bool lead = (l16 == 0) || (rprev != rC);

        // coord partial scatter: 4 f32 atomics per leader (ws, L2-merged)
        if (lead && lq == 0) {
#pragma unroll
            for (int rr = 0; rr < 4; ++rr)
                atomicAdd(&cacc[(size_t)rC * 4 + rr], pg[4][rr]);
        }

        // agg partial scatter: pk-bf16 rows into ws, two leaders per 64-lane op
        {
            unsigned m = (unsigned)(__ballot(lead) & 0xFFFFull);
            const int cp = lane & 31;
            const int half = lane >> 5;
            while (m) {
                int s0 = __builtin_ctz(m); m &= m - 1;
                int s1 = 16;
                if (m) { s1 = __builtin_ctz(m); m &= m - 1; }
                int s = half ? s1 : s0;
                if (s < 16) {
                    int rw = __shfl(rC, s, 64);
                    unsigned pkd = st[cp * 16 + (s ^ (cp & 12))];
                    atom_pk(aggb + (size_t)rw * 64 + cp * 2, pkd);
                }
            }
        }

        // ---- rotate
        tile = t1; t1 = tile + stride;
        rC = rN; cC = cN; rN = rNN; cN = cNN;
        hr0 = nr0; hr1 = nr1; hc0 = nc0; hc1 = nc1;
        px = npx; py = npy; pz = npz;
    }
}

// ===================== FALLBACK EDGE PASS (atomic, f32) =====================
__global__ __launch_bounds__(512, 4) void egcl_edge_fb(
    const float* __restrict__ h, const float* __restrict__ coord,
    const int* __restrict__ erow, const int* __restrict__ ecol,
    const float* __restrict__ We1, const float* __restrict__ be1,
    const float* __restrict__ We2, const float* __restrict__ be2,
    const float* __restrict__ Wc1, const float* __restrict__ bc1,
    const float* __restrict__ Wc2,
    float* __restrict__ aggf, float* __restrict__ cacc, int E)
{
    __shared__ __align__(16) unsigned short A1[16 * 512];
    __shared__ __align__(16) unsigned short A2[8 * 512];
    __shared__ __align__(16) unsigned short A3[8 * 512];
    __shared__ __align__(16) float bv[5][64];

    const int t = threadIdx.x;
    for (int i = t; i < 8192; i += 512) {
        int j = i & 7, lane = (i >> 3) & 63, fi = i >> 9;
        int mt = fi >> 2, ks = fi & 3;
        int in_ch = ks * 32 + ((lane >> 4) << 3) + j;
        int out   = mt * 16 + (lane & 15);
        A1[i] = f2b(We1[in_ch * 64 + out]);
    }
    for (int i = t; i < 4096; i += 512) {
        int j = i & 7, lane = (i >> 3) & 63, fi = i >> 9;
        int mt = fi >> 1, ks = fi & 1;
        int c   = (ks * 2 + (j >> 2)) * 16 + ((lane >> 4) & 3) * 4 + (j & 3);
        int out = mt * 16 + (lane & 15);
        A2[i] = f2b(We2[c * 64 + out]);
        A3[i] = f2b(Wc1[c * 64 + out]);
    }
    if (t < 64) {
        bv[0][t] = be1[t]; bv[1][t] = We1[128 * 64 + t];
        bv[2][t] = be2[t]; bv[3][t] = bc1[t]; bv[4][t] = Wc2[t];
    }
    __syncthreads();

    const int lane = t & 63;
    const int l16 = lane & 15, lq = lane >> 4;
    const int stride = gridDim.x * 8;
    const int wid = (blockIdx.x << 3) + (t >> 6);
    const int ntile = E >> 4;

    for (int tile = wid; tile < ntile; tile += stride) {
        const int e = (tile << 4) + l16;
        const int r = erow[e], c = ecol[e];
        const float* pr = coord + (size_t)r * 3;
        const float* pc = coord + (size_t)c * 3;
        float dx = pr[0] - pc[0], dy = pr[1] - pc[1], dz = pr[2] - pc[2];
        float rad = dx * dx + dy * dy + dz * dz;
        const f32x4* hr = reinterpret_cast<const f32x4*>(h + (size_t)r * 64);
        const f32x4* hc = reinterpret_cast<const f32x4*>(h + (size_t)c * 64);
        bf16x8 bR[2], bC[2];
#pragma unroll
        for (int ks = 0; ks < 2; ++ks) {
            bR[ks] = cvt8(hr[ks * 8 + lq * 2], hr[ks * 8 + lq * 2 + 1]);
            bC[ks] = cvt8(hc[ks * 8 + lq * 2], hc[ks * 8 + lq * 2 + 1]);
        }
        f32x4 a1[4];
#pragma unroll
        for (int mt = 0; mt < 4; ++mt)
            a1[mt] = *reinterpret_cast<const f32x4*>(&bv[0][mt * 16 + lq * 4]);
#pragma unroll
        for (int ks = 0; ks < 2; ++ks)
#pragma unroll
            for (int mt = 0; mt < 4; ++mt)
                a1[mt] = mfma16(ldsA(A1, mt * 4 + ks, lane), bR[ks], a1[mt]);
#pragma unroll
        for (int ks = 0; ks < 2; ++ks)
#pragma unroll
            for (int mt = 0; mt < 4; ++mt)
                a1[mt] = mfma16(ldsA(A1, mt * 4 + 2 + ks, lane), bC[ks], a1[mt]);
#pragma unroll
        for (int mt = 0; mt < 4; ++mt) {
            f32x4 wv = *reinterpret_cast<const f32x4*>(&bv[1][mt * 16 + lq * 4]);
#pragma unroll
            for (int rr = 0; rr < 4; ++rr)
                a1[mt][rr] = fmaxf(a1[mt][rr] + rad * wv[rr], 0.f);
        }
        bf16x8 b2[2] = { cvt8(a1[0], a1[1]), cvt8(a1[2], a1[3]) };
        f32x4 a2[4];
#pragma unroll
        for (int mt = 0; mt < 4; ++mt)
            a2[mt] = *reinterpret_cast<const f32x4*>(&bv[2][mt * 16 + lq * 4]);
#pragma unroll
        for (int ks = 0; ks < 2; ++ks)
#pragma unroll
            for (int mt = 0; mt < 4; ++mt)
                a2[mt] = mfma16(ldsA(A2, mt * 2 + ks, lane), b2[ks], a2[mt]);
#pragma unroll
        for (int mt = 0; mt < 4; ++mt)
#pragma unroll
            for (int rr = 0; rr < 4; ++rr) {
                a2[mt][rr] = fmaxf(a2[mt][rr], 0.f);
                atomicAdd(&aggf[(size_t)r * 64 + mt * 16 + lq * 4 + rr], a2[mt][rr]);
            }
        bf16x8 b3[2] = { cvt8(a2[0], a2[1]), cvt8(a2[2], a2[3]) };
        f32x4 a3[4];
#pragma unroll
        for (int mt = 0; mt < 4; ++mt)
            a3[mt] = *reinterpret_cast<const f32x4*>(&bv[3][mt * 16 + lq * 4]);
#pragma unroll
        for (int ks = 0; ks < 2; ++ks)
#pragma unroll
            for (int mt = 0; mt < 4; ++mt)
                a3[mt] = mfma16(ldsA(A3, mt * 2 + ks, lane), b3[ks], a3[mt]);
        float gg = 0.f;
#pragma unroll
        for (int mt = 0; mt < 4; ++mt) {
            f32x4 wv = *reinterpret_cast<const f32x4*>(&bv[4][mt * 16 + lq * 4]);
#pragma unroll
            for (int rr = 0; rr < 4; ++rr)
                gg += fmaxf(a3[mt][rr], 0.f) * wv[rr];
        }
        gg += __shfl_xor(gg, 16, 64);
        gg += __shfl_xor(gg, 32, 64);
        float dsel = (lq == 0) ? dx : (lq == 1) ? dy : dz;
        float val  = (lq == 3) ? 1.0f : fminf(fmaxf(dsel * gg, -100.f), 100.f);
        atomicAdd(&cacc[(size_t)r * 4 + lq], val);
    }
}

// ============================== NODE PASS ==============================
__device__ inline void stage_wblock(unsigned short* dst, const float* src, int t, int nthr) {
    for (int i = t; i < 4096; i += nthr) {
        int k = i >> 6, n = i & 63;
        int pos = (((n >> 4) * 2 + (k >> 5)) * 64 + ((((k >> 3) & 3) << 4) | (n & 15))) * 8 + (k & 7);
        dst[pos] = f2b(src[i]);
    }
}

__device__ inline bf16x8 ldsB(const unsigned short* base, int nt, int ks, int lane) {
    return __builtin_bit_cast(bf16x8,
        *reinterpret_cast<const u16x8*>(base + (((nt * 2 + ks) * 64 + lane) << 3)));
}

template<bool PK>
__global__ __launch_bounds__(256) void egcl_node(
    const float* __restrict__ h, const unsigned short* __restrict__ hb,
    const float* __restrict__ aggf, const unsigned short* __restrict__ aggb,
    const float* __restrict__ Wn1, const float* __restrict__ bn1,
    const float* __restrict__ Wn2, const float* __restrict__ bn2,
    const float* __restrict__ cacc, float* __restrict__ cout,
    float* __restrict__ hout, int N)
{
    __shared__ __align__(16) unsigned short wlds[3][4096];
    __shared__ __align__(16) unsigned short mlds[4][16 * 72];
    __shared__ float bn1l[64], bn2l[64];

    const int t = threadIdx.x;
    stage_wblock(wlds[0], Wn1, t, 256);
    stage_wblock(wlds[1], Wn1 + 64 * 64, t, 256);
    stage_wblock(wlds[2], Wn2, t, 256);
    if (t < 64) { bn1l[t] = bn1[t]; bn2l[t] = bn2[t]; }
    __syncthreads();

    const int wave = t >> 6, lane = t & 63;
    const int l16 = lane & 15, lq = lane >> 4;
    const int ntile = N >> 4;
    unsigned short* ml = mlds[wave];

    for (int tile = blockIdx.x * 4 + wave; tile < ntile; tile += gridDim.x * 4) {
        const int nb = tile << 4;
        bf16x8 fH[2], fA[2];
        if constexpr (PK) {
            const u16x8* ph = reinterpret_cast<const u16x8*>(hb + (size_t)(nb + l16) * 64);
            const u16x8* pa = reinterpret_cast<const u16x8*>(aggb + (size_t)(nb + l16) * 64);
#pragma unroll
            for (int ks = 0; ks < 2; ++ks) {
                fH[ks] = __builtin_bit_cast(bf16x8, ph[ks * 4 + lq]);
                fA[ks] = __builtin_bit_cast(bf16x8, pa[ks * 4 + lq]);
            }
        } else {
            const f32x4* ph = reinterpret_cast<const f32x4*>(h + (size_t)(nb + l16) * 64);
            const f32x4* pa = reinterpret_cast<const f32x4*>(aggf + (size_t)(nb + l16) * 64);
#pragma unroll
            for (int ks = 0; ks < 2; ++ks) {
                fH[ks] = cvt8(ph[ks * 8 + lq * 2], ph[ks * 8 + lq * 2 + 1]);
                fA[ks] = cvt8(pa[ks * 8 + lq * 2], pa[ks * 8 + lq * 2 + 1]);
            }
        }
        f32x4 acc[4];
#pragma unroll
        for (int nt = 0; nt < 4; ++nt) { float b = bn1l[nt * 16 + l16]; acc[nt] = (f32x4){b, b, b, b}; }
#pragma unroll
        for (int ks = 0; ks < 2; ++ks)
#pragma unroll
            for (int nt = 0; nt < 4; ++nt)
                acc[nt] = mfma16(fH[ks], ldsB(wlds[0], nt, ks, lane), acc[nt]);
#pragma unroll
        for (int ks = 0; ks < 2; ++ks)
#pragma unroll
            for (int nt = 0; nt < 4; ++nt)
                acc[nt] = mfma16(fA[ks], ldsB(wlds[1], nt, ks, lane), acc[nt]);
#pragma unroll
        for (int nt = 0; nt < 4; ++nt)
#pragma unroll
            for (int r = 0; r < 4; ++r)
                ml[(lq * 4 + r) * 72 + nt * 16 + l16] = f2b(fmaxf(acc[nt][r], 0.f));
        bf16x8 fM[2];
#pragma unroll
        for (int ks = 0; ks < 2; ++ks)
            fM[ks] = __builtin_bit_cast(bf16x8,
                *reinterpret_cast<const u16x8*>(ml + l16 * 72 + ks * 32 + lq * 8));
        f32x4 acc2[4];
#pragma unroll
        for (int nt = 0; nt < 4; ++nt) { float b = bn2l[nt * 16 + l16]; acc2[nt] = (f32x4){b, b, b, b}; }
#pragma unroll
        for (int ks = 0; ks < 2; ++ks)
#pragma unroll
            for (int nt = 0; nt < 4; ++nt)
                acc2[nt] = mfma16(fM[ks], ldsB(wlds[2], nt, ks, lane), acc2[nt]);
#pragma unroll
        for (int nt = 0; nt < 4; ++nt)
#pragma unroll
            for (int r = 0; r < 4; ++r) {
                size_t idx = (size_t)(nb + lq * 4 + r) * 64 + nt * 16 + l16;
                hout[idx] = h[idx] + acc2[nt][r];
            }
        if constexpr (PK) {
            // fused coord epilogue: one node per l16 lane (lq==0)
            if (lq == 0) {
                f32x4 cc = *reinterpret_cast<const f32x4*>(cacc + (size_t)(nb + l16) * 4);
                float inv = 1.f / fmaxf(cc[3], 1.f);
                cout[(size_t)(nb + l16) * 3 + 0] = cc[0] * inv;
                cout[(size_t)(nb + l16) * 3 + 1] = cc[1] * inv;
                cout[(size_t)(nb + l16) * 3 + 2] = cc[2] * inv;
            }
        }
    }
}

// ---------------------------------------------------------------- helpers
__global__ void egcl_coord(const float* __restrict__ cacc, float* __restrict__ cout, int N)
{
    int n = blockIdx.x * 256 + threadIdx.x;
    if (n < N) {
        f32x4 c = *reinterpret_cast<const f32x4*>(cacc + (size_t)n * 4);
        float inv = 1.f / fmaxf(c[3], 1.f);
        cout[n * 3 + 0] = c[0] * inv;
        cout[n * 3 + 1] = c[1] * inv;
        cout[n * 3 + 2] = c[2] * inv;
    }
}

extern "C" void kernel_launch(void* const* d_in, const int* in_sizes, int n_in,
                              void* d_out, int out_size, void* d_ws, size_t ws_size,
                              hipStream_t stream)
{
    const float* h     = (const float*)d_in[0];
    const float* coord = (const float*)d_in[1];
    const int*   eidx  = (const int*)d_in[2];
    const float* We1 = (const float*)d_in[3];  const float* be1 = (const float*)d_in[4];
    const float* We2 = (const float*)d_in[5];  const float* be2 = (const float*)d_in[6];
    const float* Wn1 = (const float*)d_in[7];  const float* bn1 = (const float*)d_in[8];
    const float* Wn2 = (const float*)d_in[9];  const float* bn2 = (const float*)d_in[10];
    const float* Wc1 = (const float*)d_in[11]; const float* bc1 = (const float*)d_in[12];
    const float* Wc2 = (const float*)d_in[13];

    const int N = in_sizes[0] / 64;
    const int E = in_sizes[2] / 2;

    float* hout = (float*)d_out;
    float* cout = hout + (size_t)N * 64;

    const int ntileN = N >> 4;
    const int nblkN  = (ntileN + 3) / 4;

    // workspace layout: cnt (dead after scan) and cacc share offset 0
    int*      cnt   = (int*)d_ws;                               // N ints
    float*    cacc  = (float*)d_ws;                             // N*4 f32 (zeroed in k_scatter)
    int*      woff  = (int*)((char*)d_ws + (800u << 10));       // N ints
    unsigned* spack = (unsigned*)((char*)d_ws + (1u << 20));    // E u32
    unsigned short* hb   = (unsigned short*)((char*)d_ws + (5u << 20));  // N*64 bf16
    unsigned short* aggb = (unsigned short*)((char*)d_ws + (12u << 20)); // N*64 bf16

    const size_t need_sorted = (12u << 20) + (size_t)N * 128;
    const bool use_sorted = (ws_size >= need_sorted) && N > 0 && (N % 16 == 0)
                            && (N <= 65536) && (E % 16 == 0)
                            && ((size_t)E * 4 <= (4u << 20));

    if (use_sorted) {
        const int n8 = N * 8;
        hipMemsetAsync(cnt, 0, (size_t)N * sizeof(int), stream);
        k_prep<<<(E + 255) / 256, 256, 0, stream>>>(h, hb, (u16x8*)aggb, eidx, cnt, n8, E);
        k_scan<<<1, 1024, 0, stream>>>(cnt, woff, N);
        k_scatter<<<(E + 255) / 256, 256, 0, stream>>>(eidx, eidx + E, woff, spack, cacc, N, E);
        egcl_edge_srt<<<2048, 512, 0, stream>>>(hb, coord, spack,
                                                We1, be1, We2, be2, Wc1, bc1, Wc2,
                                                aggb, cacc, E);
        egcl_node<true><<<256, 256, 0, stream>>>(h, hb, nullptr, aggb,
                                                 Wn1, bn1, Wn2, bn2, cacc, cout, hout, N);
    } else {
        float* aggf = hout;
        hipMemsetAsync(cacc, 0, (size_t)N * 4 * sizeof(float), stream);
        hipMemsetAsync(aggf, 0, (size_t)N * 64 * sizeof(float), stream);
        egcl_edge_fb<<<2048, 512, 0, stream>>>(h, coord, eidx, eidx + E,
                                               We1, be1, We2, be2, Wc1, bc1, Wc2,
                                               aggf, cacc, E);
        egcl_node<false><<<nblkN, 256, 0, stream>>>(h, nullptr, aggf, nullptr,
                                                    Wn1, bn1, Wn2, bn2, nullptr, nullptr, hout, N);
        egcl_coord<<<(N + 255) / 256, 256, 0, stream>>>(cacc, cout, N);
    }
}

// Round 7
// 232.195 us; speedup vs baseline: 1.2808x; 1.2808x over previous
//
#include <hip/hip_runtime.h>

typedef float  f32x4  __attribute__((ext_vector_type(4)));
typedef __bf16 bf16x8 __attribute__((ext_vector_type(8)));
typedef unsigned short u16x8 __attribute__((ext_vector_type(8)));
typedef unsigned int   u32x4 __attribute__((ext_vector_type(4)));

__device__ inline unsigned short f2b(float f) {
    unsigned u = __builtin_bit_cast(unsigned, f);
    u += 0x7fffu + ((u >> 16) & 1u);       // round-to-nearest-even
    return (unsigned short)(u >> 16);
}

// single-instruction packed f32->bf16 (RTNE, low half = first operand)
__device__ inline unsigned cvtpk(float a, float b) {
    unsigned r;
    asm("v_cvt_pk_bf16_f32 %0, %1, %2" : "=v"(r) : "v"(a), "v"(b));
    return r;
}

__device__ inline f32x4 mfma16(bf16x8 a, bf16x8 b, f32x4 c) {
    return __builtin_amdgcn_mfma_f32_16x16x32_bf16(a, b, c, 0, 0, 0);
}

__device__ inline bf16x8 cvt8(f32x4 a, f32x4 b) {
    u32x4 w;
    w[0] = cvtpk(a[0], a[1]); w[1] = cvtpk(a[2], a[3]);
    w[2] = cvtpk(b[0], b[1]); w[3] = cvtpk(b[2], b[3]);
    return __builtin_bit_cast(bf16x8, w);
}

__device__ inline bf16x8 ldsA(const unsigned short* base, int frag, int lane) {
    return __builtin_bit_cast(bf16x8,
        *reinterpret_cast<const u16x8*>(base + ((frag * 64 + lane) << 3)));
}

__device__ inline void atom_pk(unsigned short* p, unsigned d) {
    asm volatile("global_atomic_pk_add_bf16 %0, %1, off" :: "v"(p), "v"(d) : "memory");
}

// ===================== CSR build (fused, parallel scan) =====================
// k_prep: f32->bf16 convert of h, zero aggb, row histogram -- one launch.
__global__ void k_prep(const float* __restrict__ h, unsigned short* __restrict__ hb,
                       u16x8* __restrict__ aggb8,
                       const int* __restrict__ erow, int* __restrict__ cnt,
                       int n8, int E)
{
    int i = blockIdx.x * 256 + threadIdx.x;
    if (i < n8) {
        const f32x4* p = reinterpret_cast<const f32x4*>(h + (size_t)i * 8);
        bf16x8 v = cvt8(p[0], p[1]);
        reinterpret_cast<u16x8*>(hb)[i] = __builtin_bit_cast(u16x8, v);
        aggb8[i] = (u16x8){0, 0, 0, 0, 0, 0, 0, 0};
    }
    if (i < E) atomicAdd(&cnt[erow[i]], 1);
}

// scanA: 128 blocks, per-block partial sums of cnt chunks (coalesced)
__global__ void k_scanA(const int* __restrict__ cnt, int* __restrict__ bsum, int N)
{
    const int b = blockIdx.x, t = threadIdx.x;
    const int chunk = (N + gridDim.x - 1) / gridDim.x;
    const int lo = b * chunk;
    const int hi = min(lo + chunk, N);
    int s = 0;
    for (int i = lo + t; i < hi; i += 256) s += cnt[i];
#pragma unroll
    for (int d = 1; d < 64; d <<= 1) s += __shfl_xor(s, d, 64);
    __shared__ int ws[4];
    if ((t & 63) == 0) ws[t >> 6] = s;
    __syncthreads();
    if (t == 0) bsum[b] = ws[0] + ws[1] + ws[2] + ws[3];
}

// scanB: 128 blocks; block b locally reduces bsum[0..b) (128 ints, cheap),
// then writes its chunk's exclusive offsets (k_scan3 logic, no k_scan2 launch)
__global__ void k_scanB(const int* __restrict__ cnt, const int* __restrict__ bsum,
                        int* __restrict__ woff, int N)
{
    const int b = blockIdx.x, t = threadIdx.x;
    __shared__ int base_sh;
    __shared__ int ws[4];
    {
        int v = (t < 128 && t < b) ? bsum[t] : 0;
#pragma unroll
        for (int d = 1; d < 64; d <<= 1) v += __shfl_xor(v, d, 64);
        if ((t & 63) == 0) ws[t >> 6] = v;
        __syncthreads();
        if (t == 0) base_sh = ws[0] + ws[1] + ws[2] + ws[3];
        __syncthreads();
    }
    const int base = base_sh;
    const int chunk = (N + gridDim.x - 1) / gridDim.x;
    const int lo = b * chunk;
    const int hi = min(lo + chunk, N);
    const int tchunk = (chunk + 255) / 256;
    const int tlo = lo + t * tchunk;
    const int thi = min(tlo + tchunk, hi);
    int s = 0;
    for (int i = tlo; i < thi; ++i) s += cnt[i];
    const int lane = t & 63, wv = t >> 6;
    int sc = s;
#pragma unroll
    for (int d = 1; d < 64; d <<= 1) { int u = __shfl_up(sc, d, 64); if (lane >= d) sc += u; }
    __shared__ int ws2[4];
    if (lane == 63) ws2[wv] = sc;
    __syncthreads();
    int wadd = 0;
#pragma unroll
    for (int k = 0; k < 4; ++k) wadd += (k < wv) ? ws2[k] : 0;
    int run = base + wadd + (sc - s);
    for (int i = tlo; i < thi; ++i) { woff[i] = run; run += cnt[i]; }
}

// scatter edges into row-sorted order (pack row|col<<16); zero cacc (fused)
__global__ void k_scatter(const int* __restrict__ erow, const int* __restrict__ ecol,
                          int* __restrict__ woff, unsigned* __restrict__ spack,
                          float* __restrict__ cacc, int N, int E)
{
    int i = blockIdx.x * 256 + threadIdx.x;
    if (i < N)
        *reinterpret_cast<f32x4*>(cacc + (size_t)i * 4) = (f32x4){0.f, 0.f, 0.f, 0.f};
    if (i < E) {
        int r = erow[i];
        int pos = atomicAdd(&woff[r], 1);
        spack[pos] = (unsigned)r | ((unsigned)ecol[i] << 16);
    }
}

// ========== SORTED EDGE PASS: R0 pipeline + sel-MFMA partials + pk-bf16
// leader atomics into workspace (L2-merged; d_out is fine-grained -- R4 lesson).
__global__ __launch_bounds__(512, 2) void egcl_edge_srt(
    const unsigned short* __restrict__ hb,
    const float* __restrict__ coord,
    const unsigned* __restrict__ spack,
    const float* __restrict__ We1, const float* __restrict__ be1,
    const float* __restrict__ We2, const float* __restrict__ be2,
    const float* __restrict__ Wc1, const float* __restrict__ bc1,
    const float* __restrict__ Wc2,
    unsigned short* __restrict__ aggb, float* __restrict__ cacc, int E)
{
    __shared__ __align__(16) unsigned short A1[16 * 512];
    __shared__ __align__(16) unsigned short A2[8 * 512];
    __shared__ __align__(16) unsigned short A3[8 * 512];
    __shared__ __align__(16) float bv[5][64];
    __shared__ __align__(16) unsigned stl[8][34 * 16];   // per-wave stash [cp][slot^swz]

    const int t = threadIdx.x;
    for (int i = t; i < 8192; i += 512) {
        int j = i & 7, lane = (i >> 3) & 63, fi = i >> 9;
        int mt = fi >> 2, ks = fi & 3;
        int in_ch = ks * 32 + ((lane >> 4) << 3) + j;
        int out   = mt * 16 + (lane & 15);
        A1[i] = f2b(We1[in_ch * 64 + out]);
    }
    for (int i = t; i < 4096; i += 512) {
        int j = i & 7, lane = (i >> 3) & 63, fi = i >> 9;
        int mt = fi >> 1, ks = fi & 1;
        int c   = (ks * 2 + (j >> 2)) * 16 + ((lane >> 4) & 3) * 4 + (j & 3);
        int out = mt * 16 + (lane & 15);
        A2[i] = f2b(We2[c * 64 + out]);
        A3[i] = f2b(Wc1[c * 64 + out]);
    }
    if (t < 64) {
        bv[0][t] = be1[t]; bv[1][t] = We1[128 * 64 + t];
        bv[2][t] = be2[t]; bv[3][t] = bc1[t]; bv[4][t] = Wc2[t];
    }
    __syncthreads();

    const int lane = t & 63;
    const int l16 = lane & 15, lq = lane >> 4;
    const int stride = gridDim.x * 8;
    const int wid = (blockIdx.x << 3) + (t >> 6);
    const int ntile = E >> 4;
    const int last = ntile - 1;
    unsigned* st = stl[t >> 6];

    int tile = wid;
    if (tile >= ntile) return;

    // ---------------- prologue: tile 0 data + tile 1 indices
    int eC = (tile << 4) + l16;
    unsigned pC = spack[eC];
    int rC = (int)(pC & 0xffffu), cC = (int)(pC >> 16);
    u16x8 hr0, hr1, hc0, hc1;
    {
        const u16x8* hr = reinterpret_cast<const u16x8*>(hb + (size_t)rC * 64);
        const u16x8* hc = reinterpret_cast<const u16x8*>(hb + (size_t)cC * 64);
        hr0 = hr[lq]; hr1 = hr[4 + lq]; hc0 = hc[lq]; hc1 = hc[4 + lq];
    }
    float px = 0.f, py = 0.f, pz = 0.f;
    if (lq < 2) {
        int node = (lq == 0) ? rC : cC;
        const float* pp = coord + (size_t)node * 3;
        px = pp[0]; py = pp[1]; pz = pp[2];
    }
    int t1 = tile + stride;
    int tn = (t1 < ntile) ? t1 : last;
    unsigned pN = spack[(tn << 4) + l16];
    int rN = (int)(pN & 0xffffu), cN = (int)(pN >> 16);

    for (; tile < ntile; ) {
        // ---- stage 1: issue next tile's h/coord loads
        u16x8 nr0, nr1, nc0, nc1;
        {
            const u16x8* hr = reinterpret_cast<const u16x8*>(hb + (size_t)rN * 64);
            const u16x8* hc = reinterpret_cast<const u16x8*>(hb + (size_t)cN * 64);
            nr0 = hr[lq]; nr1 = hr[4 + lq]; nc0 = hc[lq]; nc1 = hc[4 + lq];
        }
        float npx = 0.f, npy = 0.f, npz = 0.f;
        if (lq < 2) {
            int node = (lq == 0) ? rN : cN;
            const float* pp = coord + (size_t)node * 3;
            npx = pp[0]; npy = pp[1]; npz = pp[2];
        }
        // ---- stage 2: issue tile+2 index loads
        int t2 = tile + 2 * stride;
        int t2c = (t2 < ntile) ? t2 : last;
        unsigned pNN = spack[(t2c << 4) + l16];
        int rNN = (int)(pNN & 0xffffu), cNN = (int)(pNN >> 16);

        // ---- stage 3: compute current tile
        float prx = __shfl(px, l16, 64), pry = __shfl(py, l16, 64), prz = __shfl(pz, l16, 64);
        float pcx = __shfl(px, 16 + l16, 64), pcy = __shfl(py, 16 + l16, 64), pcz = __shfl(pz, 16 + l16, 64);
        float dx = prx - pcx, dy = pry - pcy, dz = prz - pcz;
        float rad = dx * dx + dy * dy + dz * dz;

        bf16x8 bR[2] = { __builtin_bit_cast(bf16x8, hr0), __builtin_bit_cast(bf16x8, hr1) };
        bf16x8 bC[2] = { __builtin_bit_cast(bf16x8, hc0), __builtin_bit_cast(bf16x8, hc1) };

        // layer 1
        f32x4 a1[4];
#pragma unroll
        for (int mt = 0; mt < 4; ++mt)
            a1[mt] = *reinterpret_cast<const f32x4*>(&bv[0][mt * 16 + lq * 4]);
#pragma unroll
        for (int ks = 0; ks < 2; ++ks)
#pragma unroll
            for (int mt = 0; mt < 4; ++mt)
                a1[mt] = mfma16(ldsA(A1, mt * 4 + ks, lane), bR[ks], a1[mt]);
#pragma unroll
        for (int ks = 0; ks < 2; ++ks)
#pragma unroll
            for (int mt = 0; mt < 4; ++mt)
                a1[mt] = mfma16(ldsA(A1, mt * 4 + 2 + ks, lane), bC[ks], a1[mt]);
#pragma unroll
        for (int mt = 0; mt < 4; ++mt) {
            f32x4 wv = *reinterpret_cast<const f32x4*>(&bv[1][mt * 16 + lq * 4]);
#pragma unroll
            for (int rr = 0; rr < 4; ++rr)
                a1[mt][rr] = fmaxf(a1[mt][rr] + rad * wv[rr], 0.f);
        }

        // layer 2
        bf16x8 b2[2] = { cvt8(a1[0], a1[1]), cvt8(a1[2], a1[3]) };
        f32x4 a2[4];
#pragma unroll
        for (int mt = 0; mt < 4; ++mt)
            a2[mt] = *reinterpret_cast<const f32x4*>(&bv[2][mt * 16 + lq * 4]);
#pragma unroll
        for (int ks = 0; ks < 2; ++ks)
#pragma unroll
            for (int mt = 0; mt < 4; ++mt)
                a2[mt] = mfma16(ldsA(A2, mt * 2 + ks, lane), b2[ks], a2[mt]);
#pragma unroll
        for (int mt = 0; mt < 4; ++mt)
#pragma unroll
            for (int rr = 0; rr < 4; ++rr)
                a2[mt][rr] = fmaxf(a2[mt][rr], 0.f);

        // ---- stash a2 (channel-pair major, swizzled): st[cp][l16 ^ (cp&12)]
#pragma unroll
        for (int mt = 0; mt < 4; ++mt) {
            int cp0 = mt * 8 + lq * 2;
            int sw  = l16 ^ (cp0 & 12);
            st[(cp0 + 0) * 16 + sw] = cvtpk(a2[mt][0], a2[mt][1]);
            st[(cp0 + 1) * 16 + sw] = cvtpk(a2[mt][2], a2[mt][3]);
        }

        // ---- gate (MFMAs overlap the stash writes)
        bf16x8 b3[2] = { cvt8(a2[0], a2[1]), cvt8(a2[2], a2[3]) };
        f32x4 a3[4];
#pragma unroll
        for (int mt = 0; mt < 4; ++mt)
            a3[mt] = *reinterpret_cast<const f32x4*>(&bv[3][mt * 16 + lq * 4]);
#pragma unroll
        for (int ks = 0; ks < 2; ++ks)
#pragma unroll
            for (int mt = 0; mt < 4; ++mt)
                a3[mt] = mfma16(ldsA(A3, mt * 2 + ks, lane), b3[ks], a3[mt]);
        float gg = 0.f;
#pragma unroll
        for (int mt = 0; mt < 4; ++mt) {
            f32x4 wv = *reinterpret_cast<const f32x4*>(&bv[4][mt * 16 + lq * 4]);
#pragma unroll
            for (int rr = 0; rr < 4; ++rr)
                gg += fmaxf(a3[mt][rr], 0.f) * wv[rr];
        }
        gg += __shfl_xor(gg, 16, 64);
        gg += __shfl_xor(gg, 32, 64);

        float dsel = (lq == 0) ? dx : (lq == 1) ? dy : dz;
        float val  = fminf(fmaxf(dsel * gg, -100.f), 100.f);

        // ---- coord stash rows {x,y},{z,1}: cp = 32, 33 (swizzle = 0 there)
        float vy = __shfl(val, 16 + l16, 64);          // y from lq==1 lane
        if (lq == 0) st[32 * 16 + l16] = cvtpk(val, vy);
        if (lq == 2) st[33 * 16 + l16] = cvtpk(val, 1.0f);

        // ---- selection fragment: sel[k][n] = (row(edge k) == row(edge n))
        u16x8 sv;
#pragma unroll
        for (int j = 0; j < 8; ++j) {
            int ks = lq * 8 + j;
            int rk = __shfl(rC, ks & 15, 64);
            sv[j] = (ks < 16 && rk == rC) ? (unsigned short)0x3F80 : (unsigned short)0;
        }
        bf16x8 self = __builtin_bit_cast(bf16x8, sv);

        // ---- per-tile partial sums: 5 MFMAs (4 channel tiles + coord tile)
        f32x4 pg[5];
#pragma unroll
        for (int k = 0; k < 5; ++k) pg[k] = (f32x4){0.f, 0.f, 0.f, 0.f};
        const int elo = (lq & 1) << 3;
#pragma unroll
        for (int tt = 0; tt < 5; ++tt) {
            int cpb = (tt < 4) ? (tt * 8 + (l16 >> 1)) : (32 + ((l16 >> 1) & 1));
            int c   = cpb & 12;
            u32x4 wa = *reinterpret_cast<const u32x4*>(st + cpb * 16 + (elo ^ c));
            u32x4 wb = *reinterpret_cast<const u32x4*>(st + cpb * 16 + ((elo + 4) ^ c));
            u16x8 av;
#pragma unroll
            for (int j = 0; j < 4; ++j) {
                av[j]     = (l16 & 1) ? (unsigned short)(wa[j] >> 16)
                                      : (unsigned short)(wa[j] & 0xffffu);
                av[4 + j] = (l16 & 1) ? (unsigned short)(wb[j] >> 16)
                                      : (unsigned short)(wb[j] & 0xffffu);
            }
            pg[tt] = mfma16(__builtin_bit_cast(bf16x8, av), self, pg[tt]);
        }

        // ---- write partials back to the stash (feat stash fully consumed)
#pragma unroll
        for (int mt = 0; mt < 4; ++mt) {
            int cp0 = mt * 8 + lq * 2;
            int sw  = l16 ^ (cp0 & 12);
            st[(cp0 + 0) * 16 + sw] = cvtpk(pg[mt][0], pg[mt][1]);
            st[(cp0 + 1) * 16 + sw] = cvtpk(pg[mt][2], pg[mt][3]);
        }

        // ---- leader detection (run starts within the tile)
        int rprev = __shfl(rC, (lane & 48) | ((l16 + 15) & 15), 64);
        bool lead = (l16 == 0) || (rprev != rC);

        // coord partial scatter: 4 f32 atomics per leader (ws, L2-merged)
        if (lead && lq == 0) {
#pragma unroll
            for (int rr = 0; rr < 4; ++rr)
                atomicAdd(&cacc[(size_t)rC * 4 + rr], pg[4][rr]);
        }

        // agg partial scatter: pk-bf16 rows into ws, two leaders per 64-lane op
        {
            unsigned m = (unsigned)(__ballot(lead) & 0xFFFFull);
            const int cp = lane & 31;
            const int half = lane >> 5;
            while (m) {
                int s0 = __builtin_ctz(m); m &= m - 1;
                int s1 = 16;
                if (m) { s1 = __builtin_ctz(m); m &= m - 1; }
                int s = half ? s1 : s0;
                if (s < 16) {
                    int rw = __shfl(rC, s, 64);
                    unsigned pkd = st[cp * 16 + (s ^ (cp & 12))];
                    atom_pk(aggb + (size_t)rw * 64 + cp * 2, pkd);
                }
            }
        }

        // ---- rotate
        tile = t1; t1 = tile + stride;
        rC = rN; cC = cN; rN = rNN; cN = cNN;
        hr0 = nr0; hr1 = nr1; hc0 = nc0; hc1 = nc1;
        px = npx; py = npy; pz = npz;
    }
}

// ===================== FALLBACK EDGE PASS (atomic, f32) =====================
__global__ __launch_bounds__(512, 4) void egcl_edge_fb(
    const float* __restrict__ h, const float* __restrict__ coord,
    const int* __restrict__ erow, const int* __restrict__ ecol,
    const float* __restrict__ We1, const float* __restrict__ be1,
    const float* __restrict__ We2, const float* __restrict__ be2,
    const float* __restrict__ Wc1, const float* __restrict__ bc1,
    const float* __restrict__ Wc2,
    float* __restrict__ aggf, float* __restrict__ cacc, int E)
{
    __shared__ __align__(16) unsigned short A1[16 * 512];
    __shared__ __align__(16) unsigned short A2[8 * 512];
    __shared__ __align__(16) unsigned short A3[8 * 512];
    __shared__ __align__(16) float bv[5][64];

    const int t = threadIdx.x;
    for (int i = t; i < 8192; i += 512) {
        int j = i & 7, lane = (i >> 3) & 63, fi = i >> 9;
        int mt = fi >> 2, ks = fi & 3;
        int in_ch = ks * 32 + ((lane >> 4) << 3) + j;
        int out   = mt * 16 + (lane & 15);
        A1[i] = f2b(We1[in_ch * 64 + out]);
    }
    for (int i = t; i < 4096; i += 512) {
        int j = i & 7, lane = (i >> 3) & 63, fi = i >> 9;
        int mt = fi >> 1, ks = fi & 1;
        int c   = (ks * 2 + (j >> 2)) * 16 + ((lane >> 4) & 3) * 4 + (j & 3);
        int out = mt * 16 + (lane & 15);
        A2[i] = f2b(We2[c * 64 + out]);
        A3[i] = f2b(Wc1[c * 64 + out]);
    }
    if (t < 64) {
        bv[0][t] = be1[t]; bv[1][t] = We1[128 * 64 + t];
        bv[2][t] = be2[t]; bv[3][t] = bc1[t]; bv[4][t] = Wc2[t];
    }
    __syncthreads();

    const int lane = t & 63;
    const int l16 = lane & 15, lq = lane >> 4;
    const int stride = gridDim.x * 8;
    const int wid = (blockIdx.x << 3) + (t >> 6);
    const int ntile = E >> 4;

    for (int tile = wid; tile < ntile; tile += stride) {
        const int e = (tile << 4) + l16;
        const int r = erow[e], c = ecol[e];
        const float* pr = coord + (size_t)r * 3;
        const float* pc = coord + (size_t)c * 3;
        float dx = pr[0] - pc[0], dy = pr[1] - pc[1], dz = pr[2] - pc[2];
        float rad = dx * dx + dy * dy + dz * dz;
        const f32x4* hr = reinterpret_cast<const f32x4*>(h + (size_t)r * 64);
        const f32x4* hc = reinterpret_cast<const f32x4*>(h + (size_t)c * 64);
        bf16x8 bR[2], bC[2];
#pragma unroll
        for (int ks = 0; ks < 2; ++ks) {
            bR[ks] = cvt8(hr[ks * 8 + lq * 2], hr[ks * 8 + lq * 2 + 1]);
            bC[ks] = cvt8(hc[ks * 8 + lq * 2], hc[ks * 8 + lq * 2 + 1]);
        }
        f32x4 a1[4];
#pragma unroll
        for (int mt = 0; mt < 4; ++mt)
            a1[mt] = *reinterpret_cast<const f32x4*>(&bv[0][mt * 16 + lq * 4]);
#pragma unroll
        for (int ks = 0; ks < 2; ++ks)
#pragma unroll
            for (int mt = 0; mt < 4; ++mt)
                a1[mt] = mfma16(ldsA(A1, mt * 4 + ks, lane), bR[ks], a1[mt]);
#pragma unroll
        for (int ks = 0; ks < 2; ++ks)
#pragma unroll
            for (int mt = 0; mt < 4; ++mt)
                a1[mt] = mfma16(ldsA(A1, mt * 4 + 2 + ks, lane), bC[ks], a1[mt]);
#pragma unroll
        for (int mt = 0; mt < 4; ++mt) {
            f32x4 wv = *reinterpret_cast<const f32x4*>(&bv[1][mt * 16 + lq * 4]);
#pragma unroll
            for (int rr = 0; rr < 4; ++rr)
                a1[mt][rr] = fmaxf(a1[mt][rr] + rad * wv[rr], 0.f);
        }
        bf16x8 b2[2] = { cvt8(a1[0], a1[1]), cvt8(a1[2], a1[3]) };
        f32x4 a2[4];
#pragma unroll
        for (int mt = 0; mt < 4; ++mt)
            a2[mt] = *reinterpret_cast<const f32x4*>(&bv[2][mt * 16 + lq * 4]);
#pragma unroll
        for (int ks = 0; ks < 2; ++ks)
#pragma unroll
            for (int mt = 0; mt < 4; ++mt)
                a2[mt] = mfma16(ldsA(A2, mt * 2 + ks, lane), b2[ks], a2[mt]);
#pragma unroll
        for (int mt = 0; mt < 4; ++mt)
#pragma unroll
            for (int rr = 0; rr < 4; ++rr) {
                a2[mt][rr] = fmaxf(a2[mt][rr], 0.f);
                atomicAdd(&aggf[(size_t)r * 64 + mt * 16 + lq * 4 + rr], a2[mt][rr]);
            }
        bf16x8 b3[2] = { cvt8(a2[0], a2[1]), cvt8(a2[2], a2[3]) };
        f32x4 a3[4];
#pragma unroll
        for (int mt = 0; mt < 4; ++mt)
            a3[mt] = *reinterpret_cast<const f32x4*>(&bv[3][mt * 16 + lq * 4]);
#pragma unroll
        for (int ks = 0; ks < 2; ++ks)
#pragma unroll
            for (int mt = 0; mt < 4; ++mt)
                a3[mt] = mfma16(ldsA(A3, mt * 2 + ks, lane), b3[ks], a3[mt]);
        float gg = 0.f;
#pragma unroll
        for (int mt = 0; mt < 4; ++mt) {
            f32x4 wv = *reinterpret_cast<const f32x4*>(&bv[4][mt * 16 + lq * 4]);
#pragma unroll
            for (int rr = 0; rr < 4; ++rr)
                gg += fmaxf(a3[mt][rr], 0.f) * wv[rr];
        }
        gg += __shfl_xor(gg, 16, 64);
        gg += __shfl_xor(gg, 32, 64);
        float dsel = (lq == 0) ? dx : (lq == 1) ? dy : dz;
        float val  = (lq == 3) ? 1.0f : fminf(fmaxf(dsel * gg, -100.f), 100.f);
        atomicAdd(&cacc[(size_t)r * 4 + lq], val);
    }
}

// ============================== NODE PASS ==============================
__device__ inline void stage_wblock(unsigned short* dst, const float* src, int t, int nthr) {
    for (int i = t; i < 4096; i += nthr) {
        int k = i >> 6, n = i & 63;
        int pos = (((n >> 4) * 2 + (k >> 5)) * 64 + ((((k >> 3) & 3) << 4) | (n & 15))) * 8 + (k & 7);
        dst[pos] = f2b(src[i]);
    }
}

__device__ inline bf16x8 ldsB(const unsigned short* base, int nt, int ks, int lane) {
    return __builtin_bit_cast(bf16x8,
        *reinterpret_cast<const u16x8*>(base + (((nt * 2 + ks) * 64 + lane) << 3)));
}

template<bool PK>
__global__ __launch_bounds__(256) void egcl_node(
    const float* __restrict__ h, const unsigned short* __restrict__ hb,
    const float* __restrict__ aggf, const unsigned short* __restrict__ aggb,
    const float* __restrict__ Wn1, const float* __restrict__ bn1,
    const float* __restrict__ Wn2, const float* __restrict__ bn2,
    const float* __restrict__ cacc, float* __restrict__ cout,
    float* __restrict__ hout, int N)
{
    __shared__ __align__(16) unsigned short wlds[3][4096];
    __shared__ __align__(16) unsigned short mlds[4][16 * 72];
    __shared__ float bn1l[64], bn2l[64];

    const int t = threadIdx.x;
    stage_wblock(wlds[0], Wn1, t, 256);
    stage_wblock(wlds[1], Wn1 + 64 * 64, t, 256);
    stage_wblock(wlds[2], Wn2, t, 256);
    if (t < 64) { bn1l[t] = bn1[t]; bn2l[t] = bn2[t]; }
    __syncthreads();

    const int wave = t >> 6, lane = t & 63;
    const int l16 = lane & 15, lq = lane >> 4;
    const int ntile = N >> 4;
    unsigned short* ml = mlds[wave];

    for (int tile = blockIdx.x * 4 + wave; tile < ntile; tile += gridDim.x * 4) {
        const int nb = tile << 4;
        bf16x8 fH[2], fA[2];
        if constexpr (PK) {
            const u16x8* ph = reinterpret_cast<const u16x8*>(hb + (size_t)(nb + l16) * 64);
            const u16x8* pa = reinterpret_cast<const u16x8*>(aggb + (size_t)(nb + l16) * 64);
#pragma unroll
            for (int ks = 0; ks < 2; ++ks) {
                fH[ks] = __builtin_bit_cast(bf16x8, ph[ks * 4 + lq]);
                fA[ks] = __builtin_bit_cast(bf16x8, pa[ks * 4 + lq]);
            }
        } else {
            const f32x4* ph = reinterpret_cast<const f32x4*>(h + (size_t)(nb + l16) * 64);
            const f32x4* pa = reinterpret_cast<const f32x4*>(aggf + (size_t)(nb + l16) * 64);
#pragma unroll
            for (int ks = 0; ks < 2; ++ks) {
                fH[ks] = cvt8(ph[ks * 8 + lq * 2], ph[ks * 8 + lq * 2 + 1]);
                fA[ks] = cvt8(pa[ks * 8 + lq * 2], pa[ks * 8 + lq * 2 + 1]);
            }
        }
        f32x4 acc[4];
#pragma unroll
        for (int nt = 0; nt < 4; ++nt) { float b = bn1l[nt * 16 + l16]; acc[nt] = (f32x4){b, b, b, b}; }
#pragma unroll
        for (int ks = 0; ks < 2; ++ks)
#pragma unroll
            for (int nt = 0; nt < 4; ++nt)
                acc[nt] = mfma16(fH[ks], ldsB(wlds[0], nt, ks, lane), acc[nt]);
#pragma unroll
        for (int ks = 0; ks < 2; ++ks)
#pragma unroll
            for (int nt = 0; nt < 4; ++nt)
                acc[nt] = mfma16(fA[ks], ldsB(wlds[1], nt, ks, lane), acc[nt]);
#pragma unroll
        for (int nt = 0; nt < 4; ++nt)
#pragma unroll
            for (int r = 0; r < 4; ++r)
                ml[(lq * 4 + r) * 72 + nt * 16 + l16] = f2b(fmaxf(acc[nt][r], 0.f));
        bf16x8 fM[2];
#pragma unroll
        for (int ks = 0; ks < 2; ++ks)
            fM[ks] = __builtin_bit_cast(bf16x8,
                *reinterpret_cast<const u16x8*>(ml + l16 * 72 + ks * 32 + lq * 8));
        f32x4 acc2[4];
#pragma unroll
        for (int nt = 0; nt < 4; ++nt) { float b = bn2l[nt * 16 + l16]; acc2[nt] = (f32x4){b, b, b, b}; }
#pragma unroll
        for (int ks = 0; ks < 2; ++ks)
#pragma unroll
            for (int nt = 0; nt < 4; ++nt)
                acc2[nt] = mfma16(fM[ks], ldsB(wlds[2], nt, ks, lane), acc2[nt]);
#pragma unroll
        for (int nt = 0; nt < 4; ++nt)
#pragma unroll
            for (int r = 0; r < 4; ++r) {
                size_t idx = (size_t)(nb + lq * 4 + r) * 64 + nt * 16 + l16;
                hout[idx] = h[idx] + acc2[nt][r];
            }
        if constexpr (PK) {
            // fused coord epilogue: one node per l16 lane (lq==0)
            if (lq == 0) {
                f32x4 cc = *reinterpret_cast<const f32x4*>(cacc + (size_t)(nb + l16) * 4);
                float inv = 1.f / fmaxf(cc[3], 1.f);
                cout[(size_t)(nb + l16) * 3 + 0] = cc[0] * inv;
                cout[(size_t)(nb + l16) * 3 + 1] = cc[1] * inv;
                cout[(size_t)(nb + l16) * 3 + 2] = cc[2] * inv;
            }
        }
    }
}

// ---------------------------------------------------------------- helpers
__global__ void egcl_coord(const float* __restrict__ cacc, float* __restrict__ cout, int N)
{
    int n = blockIdx.x * 256 + threadIdx.x;
    if (n < N) {
        f32x4 c = *reinterpret_cast<const f32x4*>(cacc + (size_t)n * 4);
        float inv = 1.f / fmaxf(c[3], 1.f);
        cout[n * 3 + 0] = c[0] * inv;
        cout[n * 3 + 1] = c[1] * inv;
        cout[n * 3 + 2] = c[2] * inv;
    }
}

extern "C" void kernel_launch(void* const* d_in, const int* in_sizes, int n_in,
                              void* d_out, int out_size, void* d_ws, size_t ws_size,
                              hipStream_t stream)
{
    const float* h     = (const float*)d_in[0];
    const float* coord = (const float*)d_in[1];
    const int*   eidx  = (const int*)d_in[2];
    const float* We1 = (const float*)d_in[3];  const float* be1 = (const float*)d_in[4];
    const float* We2 = (const float*)d_in[5];  const float* be2 = (const float*)d_in[6];
    const float* Wn1 = (const float*)d_in[7];  const float* bn1 = (const float*)d_in[8];
    const float* Wn2 = (const float*)d_in[9];  const float* bn2 = (const float*)d_in[10];
    const float* Wc1 = (const float*)d_in[11]; const float* bc1 = (const float*)d_in[12];
    const float* Wc2 = (const float*)d_in[13];

    const int N = in_sizes[0] / 64;
    const int E = in_sizes[2] / 2;

    float* hout = (float*)d_out;
    float* cout = hout + (size_t)N * 64;

    const int ntileN = N >> 4;
    const int nblkN  = (ntileN + 3) / 4;

    // workspace layout: cnt (dead after scan) and cacc share offset 0
    int*      cnt   = (int*)d_ws;                               // N ints
    float*    cacc  = (float*)d_ws;                             // N*4 f32 (zeroed in k_scatter)
    int*      woff  = (int*)((char*)d_ws + (800u << 10));       // N ints
    int*      bsum  = (int*)((char*)d_ws + (1016u << 10));      // 128 ints
    unsigned* spack = (unsigned*)((char*)d_ws + (1u << 20));    // E u32
    unsigned short* hb   = (unsigned short*)((char*)d_ws + (5u << 20));  // N*64 bf16
    unsigned short* aggb = (unsigned short*)((char*)d_ws + (12u << 20)); // N*64 bf16

    const size_t need_sorted = (12u << 20) + (size_t)N * 128;
    const bool use_sorted = (ws_size >= need_sorted) && N > 0 && (N % 16 == 0)
                            && (N <= 65536) && (E % 16 == 0)
                            && ((size_t)E * 4 <= (4u << 20));

    if (use_sorted) {
        const int n8 = N * 8;
        hipMemsetAsync(cnt, 0, (size_t)N * sizeof(int), stream);
        k_prep<<<(E + 255) / 256, 256, 0, stream>>>(h, hb, (u16x8*)aggb, eidx, cnt, n8, E);
        k_scanA<<<128, 256, 0, stream>>>(cnt, bsum, N);
        k_scanB<<<128, 256, 0, stream>>>(cnt, bsum, woff, N);
        k_scatter<<<(E + 255) / 256, 256, 0, stream>>>(eidx, eidx + E, woff, spack, cacc, N, E);
        egcl_edge_srt<<<2048, 512, 0, stream>>>(hb, coord, spack,
                                                We1, be1, We2, be2, Wc1, bc1, Wc2,
                                                aggb, cacc, E);
        egcl_node<true><<<nblkN, 256, 0, stream>>>(h, hb, nullptr, aggb,
                                                   Wn1, bn1, Wn2, bn2, cacc, cout, hout, N);
    } else {
        float* aggf = hout;
        hipMemsetAsync(cacc, 0, (size_t)N * 4 * sizeof(float), stream);
        hipMemsetAsync(aggf, 0, (size_t)N * 64 * sizeof(float), stream);
        egcl_edge_fb<<<2048, 512, 0, stream>>>(h, coord, eidx, eidx + E,
                                               We1, be1, We2, be2, Wc1, bc1, Wc2,
                                               aggf, cacc, E);
        egcl_node<false><<<nblkN, 256, 0, stream>>>(h, nullptr, aggf, nullptr,
                                                    Wn1, bn1, Wn2, bn2, nullptr, nullptr, hout, N);
        egcl_coord<<<(N + 255) / 256, 256, 0, stream>>>(cacc, cout, N);
    }
}